// Round 7
// baseline (250.231 us; speedup 1.0000x reference)
//
#include <hip/hip_runtime.h>
#include <hip/hip_bf16.h>
#include <math.h>

#define NTOK 8192     // B*L
#define DIM  1024     // D
#define VDIM 32       // V
#define KCODES 4096   // K

// hp is pre-scaled by 2*log2(e): score MFMA yields c*s, softmax weight = exp2(c*s) = e^{2s}.
#define SC 2.8853900817779268f

typedef __attribute__((ext_vector_type(8))) short short8;
typedef __attribute__((ext_vector_type(4))) float f32x4;
typedef __attribute__((ext_vector_type(2))) float f32x2;

// MFMA16(A,B,C): D[row 4q+r = A-row][col m = B-row]; A-frag lane(q,m) holds
// A[m][k=q*8+j], B-frag lane(q,m) holds B[n=m][k=q*8+j]. (verified R2-R9)
#define MFMA16(A,B,C) __builtin_amdgcn_mfma_f32_16x16x32_bf16(A, B, C, 0, 0, 0)

__device__ __forceinline__ unsigned short f2bf(float x) {
    unsigned u = __builtin_bit_cast(unsigned, x);
    u += 0x7FFF + ((u >> 16) & 1);              // RTNE (finite inputs only)
    return (unsigned short)(u >> 16);
}
__device__ __forceinline__ float bf2f(unsigned short b) {
    unsigned u = ((unsigned)b) << 16;
    return __builtin_bit_cast(float, u);
}
__device__ __forceinline__ float fexp2(float x) {
#if __has_builtin(__builtin_amdgcn_exp2f)
    return __builtin_amdgcn_exp2f(x);
#else
    return __expf(0.6931471805599453f * x);
#endif
}

struct U4 { unsigned x, y, z, w; };

// split 8 fp32 -> bf16 hi/lo fragments (RTNE; element j of frag = p[j])
__device__ __forceinline__ void split8(const float* p, short8* H, short8* L) {
    unsigned hh[4], ll[4];
    #pragma unroll
    for (int i = 0; i < 4; ++i) {
        unsigned short a = f2bf(p[2 * i]);
        unsigned short b = f2bf(p[2 * i + 1]);
        hh[i] = (unsigned)a | ((unsigned)b << 16);
        unsigned short la = f2bf(p[2 * i] - bf2f(a));
        unsigned short lb = f2bf(p[2 * i + 1] - bf2f(b));
        ll[i] = (unsigned)la | ((unsigned)lb << 16);
    }
    U4 uh = {hh[0], hh[1], hh[2], hh[3]};
    U4 ul = {ll[0], ll[1], ll[2], ll[3]};
    *H = __builtin_bit_cast(short8, uh);
    *L = __builtin_bit_cast(short8, ul);
}

// pack 8 positive fp32 -> bf16 (round-half-up) via v_perm: 8 adds + 4 perms
__device__ __forceinline__ short8 pack8(const float* p) {
    unsigned u[8];
    #pragma unroll
    for (int j = 0; j < 8; ++j) u[j] = __builtin_bit_cast(unsigned, p[j]) + 0x8000u;
    U4 uh;
    uh.x = __builtin_amdgcn_perm(u[1], u[0], 0x07060302);
    uh.y = __builtin_amdgcn_perm(u[3], u[2], 0x07060302);
    uh.z = __builtin_amdgcn_perm(u[5], u[4], 0x07060302);
    uh.w = __builtin_amdgcn_perm(u[7], u[6], 0x07060302);
    return __builtin_bit_cast(short8, uh);
}

// LDS chunk swizzle for the E tile (row pad 40 u16 + XOR'd 16B chunk index):
// spreads the sigma-permuted b128 reads across bank groups.
__device__ __forceinline__ int lsw(int row, int j) {
    int s = ((row >> 1) ^ (row >> 3)) & 3;
    return row * 40 + ((j ^ s) * 8);
}

// ---------------------------------------------------------------------------
// ws layout: u16 region then f32 region
// ---------------------------------------------------------------------------
#define OFS_E_HI   0          // E  [4096][32]
#define OFS_E_LO   131072
#define OFS_ET_HI  262144     // Et [32][4096] (hi only; PV drops the lo term)
#define OFS_WPI_HI 458752     // Wpi [1024][32]
#define OFS_WPI_LO 491520
#define OFS_HP_HI  524288     // hp  [8192][32] (scaled by SC)
#define OFS_HP_LO  786432
#define F32_BASE   1048576    // u16 units -> float* fbase
#define NSPLIT 8
#define FOFS_HVP 0            // [8][8192][32] fp32 partial hv
#define FOFS_LP  2097152      // [8][8192]
#define FOFS_AMP 2162688      // [8][8192]
#define FOFS_AIP 2228224      // [8][8192] (int)
#define FOFS_CNT 2293760      // [256] int last-finisher counters (per 32-tok group)

// ---------------------------------------------------------------------------
// k_proj: hp = h @ Wp^T + bp, L2-normalize, scale by SC, write bf16 hi/lo.
// 512 proj blocks x 256 threads; 16 tokens/block. Wp split to bf16 hi/lo
// in-register (bit-identical fragments; k_prep dispatch deleted in R6).
// Blocks 512..591: emb normalize -> E hi/lo + Et hi (64 blocks; block 512
// also zeroes the R7 last-finisher counters) and Wpi split (16 blocks).
// ---------------------------------------------------------------------------
__global__ __launch_bounds__(256) void k_proj(const float* __restrict__ h,
                                              const float* __restrict__ Wp,
                                              const float* __restrict__ bp,
                                              const float* __restrict__ emb,
                                              const float* __restrict__ Wpi,
                                              unsigned short* __restrict__ W,
                                              unsigned short* __restrict__ hp_hi,
                                              unsigned short* __restrict__ hp_lo,
                                              int* __restrict__ cnt,
                                              float* __restrict__ loss_out) {
    __shared__ __align__(16) float red[4][16][36];
    __shared__ __align__(16) unsigned short Th[32][72];
    int tid = threadIdx.x;
    if (blockIdx.x >= 512) {              // ---- folded prep blocks ----
        int bid2 = blockIdx.x - 512;
        if (bid2 < 64) {                  // E/Et: 64 codes per block
            if (bid2 == 0) {
                cnt[tid] = 0;             // zero 256 group counters (R7)
                if (tid == 0) loss_out[0] = 0.0f;
            }
            int cb = bid2 * 64;
            int c = tid >> 2, s = tid & 3;
            const float* src = emb + (size_t)(cb + c) * VDIM + s * 8;
            float4 a = *(const float4*)src;
            float4 b = *(const float4*)(src + 4);
            float ps = a.x*a.x + a.y*a.y + a.z*a.z + a.w*a.w
                     + b.x*b.x + b.y*b.y + b.z*b.z + b.w*b.w;
            ps += __shfl_xor(ps, 1);
            ps += __shfl_xor(ps, 2);
            float inv = 1.0f / sqrtf(ps);
            float vals[8] = {a.x*inv, a.y*inv, a.z*inv, a.w*inv,
                             b.x*inv, b.y*inv, b.z*inv, b.w*inv};
            short8 H, L;
            split8(vals, &H, &L);
            *(short8*)(W + OFS_E_HI + (size_t)(cb + c) * VDIM + s * 8) = H;
            *(short8*)(W + OFS_E_LO + (size_t)(cb + c) * VDIM + s * 8) = L;
            #pragma unroll
            for (int j = 0; j < 8; ++j) Th[s * 8 + j][c] = f2bf(vals[j]);
            __syncthreads();
            int row = tid >> 3, seg = tid & 7;
            *(short8*)(W + OFS_ET_HI + (size_t)row * KCODES + cb + seg * 8) =
                *(const short8*)&Th[row][seg * 8];
        } else {                          // Wpi split: 16 blocks x 2048
            int i0 = (bid2 - 64) * 2048 + tid * 8;
            float4 a = *(const float4*)(Wpi + i0);
            float4 b = *(const float4*)(Wpi + i0 + 4);
            float vals[8] = {a.x, a.y, a.z, a.w, b.x, b.y, b.z, b.w};
            short8 H, L;
            split8(vals, &H, &L);
            *(short8*)(W + OFS_WPI_HI + i0) = H;
            *(short8*)(W + OFS_WPI_LO + i0) = L;
        }
        return;
    }
    int w = tid >> 6, l = tid & 63, q = l >> 4, m = l & 15;
    int tok0 = blockIdx.x * 16;
    const f32x4 zero4 = {0.f, 0.f, 0.f, 0.f};
    f32x4 acc0 = zero4, acc1 = zero4;
    const float* hb = h + (size_t)(tok0 + m) * DIM + w * 256 + q * 8;
    const float* wp0 = Wp + (size_t)m * DIM + w * 256 + q * 8;
    const float* wp1 = wp0 + (size_t)16 * DIM;
    #pragma unroll
    for (int c = 0; c < 8; ++c) {
        float4 a = *(const float4*)(hb + c * 32);
        float4 b = *(const float4*)(hb + c * 32 + 4);
        float va[8] = {a.x, a.y, a.z, a.w, b.x, b.y, b.z, b.w};
        short8 Bh, Bl;
        split8(va, &Bh, &Bl);
        float4 w0a = *(const float4*)(wp0 + c * 32);
        float4 w0b = *(const float4*)(wp0 + c * 32 + 4);
        float v0[8] = {w0a.x, w0a.y, w0a.z, w0a.w, w0b.x, w0b.y, w0b.z, w0b.w};
        short8 A0h, A0l;
        split8(v0, &A0h, &A0l);
        float4 w1a = *(const float4*)(wp1 + c * 32);
        float4 w1b = *(const float4*)(wp1 + c * 32 + 4);
        float v1[8] = {w1a.x, w1a.y, w1a.z, w1a.w, w1b.x, w1b.y, w1b.z, w1b.w};
        short8 A1h, A1l;
        split8(v1, &A1h, &A1l);
        acc0 = MFMA16(A0l, Bl, acc0); acc0 = MFMA16(A0l, Bh, acc0);
        acc0 = MFMA16(A0h, Bl, acc0); acc0 = MFMA16(A0h, Bh, acc0);
        acc1 = MFMA16(A1l, Bl, acc1); acc1 = MFMA16(A1l, Bh, acc1);
        acc1 = MFMA16(A1h, Bl, acc1); acc1 = MFMA16(A1h, Bh, acc1);
    }
    *(f32x4*)&red[w][m][4 * q]      = acc0;   // v = 4q+r, token m
    *(f32x4*)&red[w][m][16 + 4 * q] = acc1;
    __syncthreads();
    #pragma unroll
    for (int half = 0; half < 2; ++half) {
        int t = (tid >> 5) + half * 8, v = tid & 31;
        float s = bp[v];
        #pragma unroll
        for (int j = 0; j < 4; ++j) s += red[j][t][v];
        float sq = s * s;
        #pragma unroll
        for (int off = 1; off < 32; off <<= 1) sq += __shfl_xor(sq, off);
        float nv = s * (SC / sqrtf(sq));
        unsigned short hb2 = f2bf(nv);
        size_t idx = (size_t)(tok0 + t) * VDIM + v;
        hp_hi[idx] = hb2;
        hp_lo[idx] = f2bf(nv - bf2f(hb2));
    }
}

// ---------------------------------------------------------------------------
// k_vq: scores (3-product split fp32) -> exp2 -> argmax -> P@E^T (hi-only),
// then (R7) FUSED k_out epilogue via last-finisher: after a block stores its
// partials it release-fences and bumps a device counter per 32-token group;
// the 8th (last) arrival acquire-fences and runs the merge+normalize+Wpi GEMM
// for that group. Merge loop order identical to the R6 k_out -> bit-identical
// output; counters zeroed by k_proj (stream-ordered before k_vq).
// 512 blocks x 256 threads (4 waves, launch_bounds(256,2)).
// ---------------------------------------------------------------------------
__global__ __launch_bounds__(256, 2) void k_vq(const unsigned short* __restrict__ W,
                                               float* __restrict__ hvp,
                                               float* __restrict__ lp,
                                               float* __restrict__ amp,
                                               int* __restrict__ aip,
                                               const float* __restrict__ mask,
                                               const float* __restrict__ bpi,
                                               int* __restrict__ cnt,
                                               float* __restrict__ out,
                                               float* __restrict__ code_out) {
    __shared__ __align__(16) unsigned short Eh[2][64 * 40];   // 20 KB total
    __shared__ __align__(16) unsigned short El[2][64 * 40];
    // fused-epilogue shared state (used after the main loop)
    __shared__ float invl[32];
    __shared__ float lred[32][9];
    __shared__ float amred[32][9];
    __shared__ int   aired[32][9];
    __shared__ __align__(16) unsigned short hvh[32][40];
    __shared__ __align__(16) unsigned short hvl[32][40];
    __shared__ int lastflag[4];

    const unsigned short* E_hi  = W + OFS_E_HI;
    const unsigned short* E_lo  = W + OFS_E_LO;
    const unsigned short* Et_hi = W + OFS_ET_HI;
    const unsigned short* hp_hi = W + OFS_HP_HI;
    const unsigned short* hp_lo = W + OFS_HP_LO;

    int tid = threadIdx.x;
    int w = tid >> 6, l = tid & 63, q = l >> 4, m = l & 15;
    int tg = blockIdx.x >> 3, sp = blockIdx.x & 7;
    int tok0 = tg * 128 + w * 32;            // wave's 32 tokens (2 tiles)
    int cb0 = sp * 512;
    int sig = ((m & 12) << 1) | (m & 3);     // sigma(m) = 8*(m>>2)+(m&3)
    const f32x4 zero4 = {0.f, 0.f, 0.f, 0.f};

    // staging: 64 codes * 4 chunk16 = 256 16B-chunks; thread -> 1 hi + 1 lo
    int cs = tid >> 2, js = tid & 3;
    int lds_off = lsw(cs, js);
    size_t gs = (size_t)cs * VDIM + js * 8;

    size_t h0 = (size_t)(tok0 + m) * VDIM + q * 8;
    short8 hph0 = *(const short8*)(hp_hi + h0);
    short8 hpl0 = *(const short8*)(hp_lo + h0);
    short8 hph1 = *(const short8*)(hp_hi + h0 + 16 * VDIM);
    short8 hpl1 = *(const short8*)(hp_lo + h0 + 16 * VDIM);

    // prologue: stage tile 0 into buf 0
    {
        size_t tb = (size_t)cb0 * VDIM;
        short8 a = *(const short8*)(E_hi + tb + gs);
        short8 b = *(const short8*)(E_lo + tb + gs);
        *(short8*)&Eh[0][lds_off] = a;
        *(short8*)&El[0][lds_off] = b;
    }
    __syncthreads();

    f32x4 hv00 = zero4, hv01 = zero4, hv10 = zero4, hv11 = zero4;
    f32x2 ls0v = {0.f, 0.f}, ls1v = {0.f, 0.f};
    float am0 = -1e30f, am1 = -1e30f;
    int ai0 = 0, ai1 = 0;

    #pragma unroll 1
    for (int t = 0; t < 8; ++t) {            // 8 LDS tiles of 64 codes
        int buf = t & 1;
        short8 sa, sb;
        if (t < 7) {                         // issue next tile's staging loads
            size_t tb = (size_t)(cb0 + (t + 1) * 64) * VDIM;
            sa = *(const short8*)(E_hi + tb + gs);
            sb = *(const short8*)(E_lo + tb + gs);
        }
        int cbase = cb0 + t * 64;
        size_t tb0 = (size_t)sig * KCODES + cbase + q * 8;
        short8 T00 = *(const short8*)(Et_hi + tb0);
        short8 T01 = *(const short8*)(Et_hi + tb0 + (size_t)4 * KCODES);
        short8 T10 = *(const short8*)(Et_hi + tb0 + 32);
        short8 T11 = *(const short8*)(Et_hi + tb0 + 32 + (size_t)4 * KCODES);
        short8 E00h = *(const short8*)&Eh[buf][lsw(sig,          q)];
        short8 E00l = *(const short8*)&El[buf][lsw(sig,          q)];
        short8 E01h = *(const short8*)&Eh[buf][lsw(sig + 4,      q)];
        short8 E01l = *(const short8*)&El[buf][lsw(sig + 4,      q)];
        short8 E10h = *(const short8*)&Eh[buf][lsw(32 + sig,     q)];
        short8 E10l = *(const short8*)&El[buf][lsw(32 + sig,     q)];
        short8 E11h = *(const short8*)&Eh[buf][lsw(32 + sig + 4, q)];
        short8 E11l = *(const short8*)&El[buf][lsw(32 + sig + 4, q)];

        // ---- phase 1: all 24 score MFMAs (8 independent 3-deep chains) ----
        f32x4 sA0, sA1, sB0, sB1, sC0, sC1, sD0, sD1;
        sA0 = MFMA16(E00h, hpl0, zero4);     // chunk0 / tile0
        sA1 = MFMA16(E01h, hpl0, zero4);
        sB0 = MFMA16(E00h, hpl1, zero4);     // chunk0 / tile1
        sB1 = MFMA16(E01h, hpl1, zero4);
        sC0 = MFMA16(E10h, hpl0, zero4);     // chunk1 / tile0
        sC1 = MFMA16(E11h, hpl0, zero4);
        sD0 = MFMA16(E10h, hpl1, zero4);     // chunk1 / tile1
        sD1 = MFMA16(E11h, hpl1, zero4);
        sA0 = MFMA16(E00l, hph0, sA0);
        sA1 = MFMA16(E01l, hph0, sA1);
        sB0 = MFMA16(E00l, hph1, sB0);
        sB1 = MFMA16(E01l, hph1, sB1);
        sC0 = MFMA16(E10l, hph0, sC0);
        sC1 = MFMA16(E11l, hph0, sC1);
        sD0 = MFMA16(E10l, hph1, sD0);
        sD1 = MFMA16(E11l, hph1, sD1);
        sA0 = MFMA16(E00h, hph0, sA0);
        sA1 = MFMA16(E01h, hph0, sA1);
        sB0 = MFMA16(E00h, hph1, sB0);
        sB1 = MFMA16(E01h, hph1, sB1);
        sC0 = MFMA16(E10h, hph0, sC0);
        sC1 = MFMA16(E11h, hph0, sC1);
        sD0 = MFMA16(E10h, hph1, sD0);
        sD1 = MFMA16(E11h, hph1, sD1);

        // ---- phase 2: exp2 -> pack -> PV -> bookkeeping (order == R0) ----
        {
            int lbase = cbase + 8 * q;
            float p[8];
            #pragma unroll
            for (int r = 0; r < 4; ++r) { p[r] = fexp2(sA0[r]); p[4 + r] = fexp2(sA1[r]); }
            short8 Ph = pack8(p);
            hv00 = MFMA16(T00, Ph, hv00);
            hv01 = MFMA16(T01, Ph, hv01);
            #pragma unroll
            for (int r = 0; r < 4; ++r) {
                float sv = sA0[r];
                if (sv > am0) { am0 = sv; ai0 = lbase + r; }
                sv = sA1[r];
                if (sv > am0) { am0 = sv; ai0 = lbase + 4 + r; }
            }
            f32x2 pa = {p[0], p[1]}, pb = {p[2], p[3]};
            f32x2 pc = {p[4], p[5]}, pd = {p[6], p[7]};
            ls0v += (pa + pb) + (pc + pd);
        }
        {
            int lbase = cbase + 8 * q;
            float p[8];
            #pragma unroll
            for (int r = 0; r < 4; ++r) { p[r] = fexp2(sB0[r]); p[4 + r] = fexp2(sB1[r]); }
            short8 Ph = pack8(p);
            hv10 = MFMA16(T00, Ph, hv10);
            hv11 = MFMA16(T01, Ph, hv11);
            #pragma unroll
            for (int r = 0; r < 4; ++r) {
                float sv = sB0[r];
                if (sv > am1) { am1 = sv; ai1 = lbase + r; }
                sv = sB1[r];
                if (sv > am1) { am1 = sv; ai1 = lbase + 4 + r; }
            }
            f32x2 pa = {p[0], p[1]}, pb = {p[2], p[3]};
            f32x2 pc = {p[4], p[5]}, pd = {p[6], p[7]};
            ls1v += (pa + pb) + (pc + pd);
        }
        {
            int lbase = cbase + 32 + 8 * q;
            float p[8];
            #pragma unroll
            for (int r = 0; r < 4; ++r) { p[r] = fexp2(sC0[r]); p[4 + r] = fexp2(sC1[r]); }
            short8 Ph = pack8(p);
            hv00 = MFMA16(T10, Ph, hv00);
            hv01 = MFMA16(T11, Ph, hv01);
            #pragma unroll
            for (int r = 0; r < 4; ++r) {
                float sv = sC0[r];
                if (sv > am0) { am0 = sv; ai0 = lbase + r; }
                sv = sC1[r];
                if (sv > am0) { am0 = sv; ai0 = lbase + 4 + r; }
            }
            f32x2 pa = {p[0], p[1]}, pb = {p[2], p[3]};
            f32x2 pc = {p[4], p[5]}, pd = {p[6], p[7]};
            ls0v += (pa + pb) + (pc + pd);
        }
        {
            int lbase = cbase + 32 + 8 * q;
            float p[8];
            #pragma unroll
            for (int r = 0; r < 4; ++r) { p[r] = fexp2(sD0[r]); p[4 + r] = fexp2(sD1[r]); }
            short8 Ph = pack8(p);
            hv10 = MFMA16(T10, Ph, hv10);
            hv11 = MFMA16(T11, Ph, hv11);
            #pragma unroll
            for (int r = 0; r < 4; ++r) {
                float sv = sD0[r];
                if (sv > am1) { am1 = sv; ai1 = lbase + r; }
                sv = sD1[r];
                if (sv > am1) { am1 = sv; ai1 = lbase + 4 + r; }
            }
            f32x2 pa = {p[0], p[1]}, pb = {p[2], p[3]};
            f32x2 pc = {p[4], p[5]}, pd = {p[6], p[7]};
            ls1v += (pa + pb) + (pc + pd);
        }

        if (t < 7) {
            int nb = buf ^ 1;
            *(short8*)&Eh[nb][lds_off] = sa;
            *(short8*)&El[nb][lds_off] = sb;
            __syncthreads();
        }
    }

    float ls0 = ls0v.x + ls0v.y;
    float ls1 = ls1v.x + ls1v.y;
    // cross-q reduce (lane bits 4,5 share token column m)
    #pragma unroll
    for (int off = 16; off <= 32; off <<= 1) {
        ls0 += __shfl_xor(ls0, off);
        float a2 = __shfl_xor(am0, off);
        int   i2 = __shfl_xor(ai0, off);
        if (a2 > am0 || (a2 == am0 && i2 < ai0)) { am0 = a2; ai0 = i2; }
        ls1 += __shfl_xor(ls1, off);
        a2 = __shfl_xor(am1, off);
        i2 = __shfl_xor(ai1, off);
        if (a2 > am1 || (a2 == am1 && i2 < ai1)) { am1 = a2; ai1 = i2; }
    }
    size_t gtok = (size_t)sp * NTOK + tok0;
    if (q == 0) {
        lp[gtok + m] = ls0;      amp[gtok + m] = am0;      aip[gtok + m] = ai0;
        lp[gtok + 16 + m] = ls1; amp[gtok + 16 + m] = am1; aip[gtok + 16 + m] = ai1;
    }
    float* dst0 = hvp + (gtok + m) * VDIM;
    *(f32x4*)(dst0 + 8 * q)     = hv00;
    *(f32x4*)(dst0 + 8 * q + 4) = hv01;
    float* dst1 = hvp + (gtok + 16 + m) * VDIM;
    *(f32x4*)(dst1 + 8 * q)     = hv10;
    *(f32x4*)(dst1 + 8 * q + 4) = hv11;

    // ---- R7 fused epilogue: last-finisher per 32-token group ----
    __threadfence();                         // release: partials visible
    __syncthreads();                         // all waves' stores+fences done
    if (tid < 4)
        lastflag[tid] = (atomicAdd(&cnt[tg * 4 + tid], 1) == NSPLIT - 1);
    __syncthreads();
    if (!(lastflag[0] | lastflag[1] | lastflag[2] | lastflag[3])) return;
    __threadfence();                         // acquire: other blocks' partials

    const unsigned short* Wpi_hi = W + OFS_WPI_HI;
    const unsigned short* Wpi_lo = W + OFS_WPI_LO;
    #pragma unroll 1
    for (int g = 0; g < 4; ++g) {
        if (!lastflag[g]) continue;          // uniform across block
        int tok0o = tg * 128 + g * 32;
        {                                    // parallel merge loads (all 256)
            int t2 = tid >> 3, s2 = tid & 7;
            size_t gi = (size_t)s2 * NTOK + tok0o + t2;
            lred[t2][s2]  = lp[gi];
            amred[t2][s2] = amp[gi];
            aired[t2][s2] = aip[gi];
        }
        __syncthreads();
        if (tid < 32) {
            float L = 0.f, A = -1e30f;
            int I = 0x7fffffff;
            #pragma unroll
            for (int s2 = 0; s2 < NSPLIT; ++s2) {
                L += lred[tid][s2];
                float a2 = amred[tid][s2];
                int   i2 = aired[tid][s2];
                if (a2 > A || (a2 == A && i2 < I)) { A = a2; I = i2; }
            }
            bool on = (mask[tok0o + tid] == 1.0f);
            code_out[tok0o + tid] = on ? (float)I : 0.0f;
            invl[tid] = on ? (1.0f / L) : 0.0f;
        }
        __syncthreads();
        {                                    // vectorized hv merge: 32t x 8 quads
            int t2 = tid >> 3, g2 = tid & 7;
            f32x4 x = zero4;
            #pragma unroll
            for (int s2 = 0; s2 < NSPLIT; ++s2)
                x += *(const f32x4*)&hvp[((size_t)s2 * NTOK + tok0o + t2) * VDIM + g2 * 4];
            float iv = invl[t2];
            #pragma unroll
            for (int j = 0; j < 4; ++j) {
                float xv = x[j] * iv;
                unsigned short hb = f2bf(xv);
                hvh[t2][g2 * 4 + j] = hb;
                hvl[t2][g2 * 4 + j] = f2bf(xv - bf2f(hb));
            }
        }
        __syncthreads();
        short8 gh0 = *(const short8*)&hvh[m][q * 8];
        short8 gl0 = *(const short8*)&hvl[m][q * 8];
        short8 gh1 = *(const short8*)&hvh[16 + m][q * 8];
        short8 gl1 = *(const short8*)&hvl[16 + m][q * 8];
        #pragma unroll
        for (int dt = 0; dt < 16; ++dt) {
            int dbase = w * 256 + dt * 16;
            short8 Ah = *(const short8*)(Wpi_hi + (size_t)(dbase + m) * VDIM + q * 8);
            short8 Al = *(const short8*)(Wpi_lo + (size_t)(dbase + m) * VDIM + q * 8);
            float4 bias = *(const float4*)(bpi + dbase + 4 * q);
            f32x4 o0 = MFMA16(Al, gh0, zero4);
            o0 = MFMA16(Ah, gl0, o0);
            o0 = MFMA16(Ah, gh0, o0);
            f32x4 o1 = MFMA16(Al, gh1, zero4);
            o1 = MFMA16(Ah, gl1, o1);
            o1 = MFMA16(Ah, gh1, o1);
            float4 r0 = make_float4(o0[0] + bias.x, o0[1] + bias.y,
                                    o0[2] + bias.z, o0[3] + bias.w);
            *(float4*)(out + (size_t)(tok0o + m) * DIM + dbase + 4 * q) = r0;
            float4 r1 = make_float4(o1[0] + bias.x, o1[1] + bias.y,
                                    o1[2] + bias.z, o1[3] + bias.w);
            *(float4*)(out + (size_t)(tok0o + 16 + m) * DIM + dbase + 4 * q) = r1;
        }
        __syncthreads();                     // shared arrays reused next g
    }
}

// ---------------------------------------------------------------------------
extern "C" void kernel_launch(void* const* d_in, const int* in_sizes, int n_in,
                              void* d_out, int out_size, void* d_ws, size_t ws_size,
                              hipStream_t stream) {
    const float* h    = (const float*)d_in[0];
    const float* mask = (const float*)d_in[1];
    const float* Wp   = (const float*)d_in[2];
    const float* bp   = (const float*)d_in[3];
    const float* Wpi  = (const float*)d_in[4];
    const float* bpi  = (const float*)d_in[5];
    const float* emb  = (const float*)d_in[6];
    float* out = (float*)d_out;

    unsigned short* W = (unsigned short*)d_ws;
    unsigned short* hp_hi = W + OFS_HP_HI;
    unsigned short* hp_lo = W + OFS_HP_LO;
    float* fbase = (float*)(W + F32_BASE);
    float* hvp = fbase + FOFS_HVP;
    float* lpp = fbase + FOFS_LP;
    float* ampp = fbase + FOFS_AMP;
    int*   aipp = (int*)(fbase + FOFS_AIP);
    int*   cntp = (int*)(fbase + FOFS_CNT);

    float* code_out = out + (size_t)NTOK * DIM;
    float* loss_out = code_out + NTOK;

    hipLaunchKernelGGL(k_proj, dim3(592), dim3(256), 0, stream, h, Wp, bp, emb, Wpi, W, hp_hi, hp_lo, cntp, loss_out);
    hipLaunchKernelGGL(k_vq,   dim3(512), dim3(256), 0, stream, W, hvp, lpp, ampp, aipp, mask, bpi, cntp, out, code_out);
}

// Round 8
// 127.695 us; speedup vs baseline: 1.9596x; 1.9596x over previous
//
#include <hip/hip_runtime.h>
#include <hip/hip_bf16.h>
#include <math.h>

#define NTOK 8192     // B*L
#define DIM  1024     // D
#define VDIM 32       // V
#define KCODES 4096   // K

// hp is pre-scaled by 2*log2(e): score MFMA yields c*s, softmax weight = exp2(c*s) = e^{2s}.
#define SC 2.8853900817779268f

typedef __attribute__((ext_vector_type(8))) short short8;
typedef __attribute__((ext_vector_type(4))) float f32x4;
typedef __attribute__((ext_vector_type(2))) float f32x2;

// MFMA16(A,B,C): D[row 4q+r = A-row][col m = B-row]; A-frag lane(q,m) holds
// A[m][k=q*8+j], B-frag lane(q,m) holds B[n=m][k=q*8+j]. (verified R2-R9)
#define MFMA16(A,B,C) __builtin_amdgcn_mfma_f32_16x16x32_bf16(A, B, C, 0, 0, 0)

__device__ __forceinline__ unsigned short f2bf(float x) {
    unsigned u = __builtin_bit_cast(unsigned, x);
    u += 0x7FFF + ((u >> 16) & 1);              // RTNE (finite inputs only)
    return (unsigned short)(u >> 16);
}
__device__ __forceinline__ float bf2f(unsigned short b) {
    unsigned u = ((unsigned)b) << 16;
    return __builtin_bit_cast(float, u);
}
__device__ __forceinline__ float fexp2(float x) {
#if __has_builtin(__builtin_amdgcn_exp2f)
    return __builtin_amdgcn_exp2f(x);
#else
    return __expf(0.6931471805599453f * x);
#endif
}

struct U4 { unsigned x, y, z, w; };

// split 8 fp32 -> bf16 hi/lo fragments (RTNE; element j of frag = p[j])
__device__ __forceinline__ void split8(const float* p, short8* H, short8* L) {
    unsigned hh[4], ll[4];
    #pragma unroll
    for (int i = 0; i < 4; ++i) {
        unsigned short a = f2bf(p[2 * i]);
        unsigned short b = f2bf(p[2 * i + 1]);
        hh[i] = (unsigned)a | ((unsigned)b << 16);
        unsigned short la = f2bf(p[2 * i] - bf2f(a));
        unsigned short lb = f2bf(p[2 * i + 1] - bf2f(b));
        ll[i] = (unsigned)la | ((unsigned)lb << 16);
    }
    U4 uh = {hh[0], hh[1], hh[2], hh[3]};
    U4 ul = {ll[0], ll[1], ll[2], ll[3]};
    *H = __builtin_bit_cast(short8, uh);
    *L = __builtin_bit_cast(short8, ul);
}

// pack 8 positive fp32 -> bf16 (round-half-up) via v_perm: 8 adds + 4 perms
__device__ __forceinline__ short8 pack8(const float* p) {
    unsigned u[8];
    #pragma unroll
    for (int j = 0; j < 8; ++j) u[j] = __builtin_bit_cast(unsigned, p[j]) + 0x8000u;
    U4 uh;
    uh.x = __builtin_amdgcn_perm(u[1], u[0], 0x07060302);
    uh.y = __builtin_amdgcn_perm(u[3], u[2], 0x07060302);
    uh.z = __builtin_amdgcn_perm(u[5], u[4], 0x07060302);
    uh.w = __builtin_amdgcn_perm(u[7], u[6], 0x07060302);
    return __builtin_bit_cast(short8, uh);
}

// LDS chunk swizzle for the E tile (row pad 40 u16 + XOR'd 16B chunk index):
// spreads the sigma-permuted b128 reads across bank groups.
__device__ __forceinline__ int lsw(int row, int j) {
    int s = ((row >> 1) ^ (row >> 3)) & 3;
    return row * 40 + ((j ^ s) * 8);
}

// ---------------------------------------------------------------------------
// ws layout: u16 region then f32 region
// ---------------------------------------------------------------------------
#define OFS_E_HI   0          // E  [4096][32]
#define OFS_E_LO   131072
#define OFS_ET_HI  262144     // Et [32][4096] (hi only; PV drops the lo term)
#define OFS_WPI_HI 458752     // Wpi [1024][32]
#define OFS_WPI_LO 491520
#define OFS_HP_HI  524288     // hp  [8192][32] (scaled by SC)
#define OFS_HP_LO  786432
#define F32_BASE   1048576    // u16 units -> float* fbase
#define NSPLIT 8
#define FOFS_HVP 0            // [8][8192][32] fp32 partial hv
#define FOFS_LP  2097152      // [8][8192]
#define FOFS_AMP 2162688      // [8][8192]
#define FOFS_AIP 2228224      // [8][8192] (int)

// ---------------------------------------------------------------------------
// k_proj: hp = h @ Wp^T + bp, L2-normalize, scale by SC, write bf16 hi/lo.
// R8: 256 proj blocks x 256 threads; 32 tokens/block (ILP-2: each wave runs
// two 16-token tiles sharing every Wp fragment -> Wp fp32 read + in-register
// split8 halved per token; same per-token MFMA chain order -> bit-identical).
// Blocks 256..335: emb normalize -> E hi/lo + Et hi (64 blocks) and Wpi
// split (16 blocks) — consumed only by k_vq/k_out, which launch later.
// R7 lesson (HW rule): NO device-scope fences/atomics in hot kernels —
// a __threadfence per block caused L2 writeback+invalidate storms (176 µs).
// Kernel boundaries are the cheap sync primitive on multi-XCD CDNA4.
// ---------------------------------------------------------------------------
__global__ __launch_bounds__(256) void k_proj(const float* __restrict__ h,
                                              const float* __restrict__ Wp,
                                              const float* __restrict__ bp,
                                              const float* __restrict__ emb,
                                              const float* __restrict__ Wpi,
                                              unsigned short* __restrict__ W,
                                              unsigned short* __restrict__ hp_hi,
                                              unsigned short* __restrict__ hp_lo,
                                              float* __restrict__ loss_out) {
    __shared__ __align__(16) float red[4][32][36];
    __shared__ __align__(16) unsigned short Th[32][72];
    int tid = threadIdx.x;
    if (blockIdx.x >= 256) {              // ---- folded prep blocks ----
        int bid2 = blockIdx.x - 256;
        if (bid2 < 64) {                  // E/Et: 64 codes per block
            if (bid2 == 0 && tid == 0) loss_out[0] = 0.0f;
            int cb = bid2 * 64;
            int c = tid >> 2, s = tid & 3;
            const float* src = emb + (size_t)(cb + c) * VDIM + s * 8;
            float4 a = *(const float4*)src;
            float4 b = *(const float4*)(src + 4);
            float ps = a.x*a.x + a.y*a.y + a.z*a.z + a.w*a.w
                     + b.x*b.x + b.y*b.y + b.z*b.z + b.w*b.w;
            ps += __shfl_xor(ps, 1);
            ps += __shfl_xor(ps, 2);
            float inv = 1.0f / sqrtf(ps);
            float vals[8] = {a.x*inv, a.y*inv, a.z*inv, a.w*inv,
                             b.x*inv, b.y*inv, b.z*inv, b.w*inv};
            short8 H, L;
            split8(vals, &H, &L);
            *(short8*)(W + OFS_E_HI + (size_t)(cb + c) * VDIM + s * 8) = H;
            *(short8*)(W + OFS_E_LO + (size_t)(cb + c) * VDIM + s * 8) = L;
            #pragma unroll
            for (int j = 0; j < 8; ++j) Th[s * 8 + j][c] = f2bf(vals[j]);
            __syncthreads();
            int row = tid >> 3, seg = tid & 7;
            *(short8*)(W + OFS_ET_HI + (size_t)row * KCODES + cb + seg * 8) =
                *(const short8*)&Th[row][seg * 8];
        } else {                          // Wpi split: 16 blocks x 2048
            int i0 = (bid2 - 64) * 2048 + tid * 8;
            float4 a = *(const float4*)(Wpi + i0);
            float4 b = *(const float4*)(Wpi + i0 + 4);
            float vals[8] = {a.x, a.y, a.z, a.w, b.x, b.y, b.z, b.w};
            short8 H, L;
            split8(vals, &H, &L);
            *(short8*)(W + OFS_WPI_HI + i0) = H;
            *(short8*)(W + OFS_WPI_LO + i0) = L;
        }
        return;
    }
    int w = tid >> 6, l = tid & 63, q = l >> 4, m = l & 15;
    int tok0 = blockIdx.x * 32;
    const f32x4 zero4 = {0.f, 0.f, 0.f, 0.f};
    f32x4 acc0 = zero4, acc1 = zero4, acc2 = zero4, acc3 = zero4;
    const float* hb0 = h + (size_t)(tok0 + m) * DIM + w * 256 + q * 8;
    const float* hb1 = hb0 + (size_t)16 * DIM;
    const float* wp0 = Wp + (size_t)m * DIM + w * 256 + q * 8;
    const float* wp1 = wp0 + (size_t)16 * DIM;
    #pragma unroll
    for (int c = 0; c < 8; ++c) {
        // token tile 0
        float4 a0 = *(const float4*)(hb0 + c * 32);
        float4 b0 = *(const float4*)(hb0 + c * 32 + 4);
        float va0[8] = {a0.x, a0.y, a0.z, a0.w, b0.x, b0.y, b0.z, b0.w};
        short8 B0h, B0l;
        split8(va0, &B0h, &B0l);
        // token tile 1
        float4 a1 = *(const float4*)(hb1 + c * 32);
        float4 b1 = *(const float4*)(hb1 + c * 32 + 4);
        float va1[8] = {a1.x, a1.y, a1.z, a1.w, b1.x, b1.y, b1.z, b1.w};
        short8 B1h, B1l;
        split8(va1, &B1h, &B1l);
        // shared Wp fragments (split in-register, bit-identical to staging)
        float4 w0a = *(const float4*)(wp0 + c * 32);
        float4 w0b = *(const float4*)(wp0 + c * 32 + 4);
        float v0[8] = {w0a.x, w0a.y, w0a.z, w0a.w, w0b.x, w0b.y, w0b.z, w0b.w};
        short8 A0h, A0l;
        split8(v0, &A0h, &A0l);
        float4 w1a = *(const float4*)(wp1 + c * 32);
        float4 w1b = *(const float4*)(wp1 + c * 32 + 4);
        float v1[8] = {w1a.x, w1a.y, w1a.z, w1a.w, w1b.x, w1b.y, w1b.z, w1b.w};
        short8 A1h, A1l;
        split8(v1, &A1h, &A1l);
        acc0 = MFMA16(A0l, B0l, acc0); acc0 = MFMA16(A0l, B0h, acc0);
        acc0 = MFMA16(A0h, B0l, acc0); acc0 = MFMA16(A0h, B0h, acc0);
        acc1 = MFMA16(A1l, B0l, acc1); acc1 = MFMA16(A1l, B0h, acc1);
        acc1 = MFMA16(A1h, B0l, acc1); acc1 = MFMA16(A1h, B0h, acc1);
        acc2 = MFMA16(A0l, B1l, acc2); acc2 = MFMA16(A0l, B1h, acc2);
        acc2 = MFMA16(A0h, B1l, acc2); acc2 = MFMA16(A0h, B1h, acc2);
        acc3 = MFMA16(A1l, B1l, acc3); acc3 = MFMA16(A1l, B1h, acc3);
        acc3 = MFMA16(A1h, B1l, acc3); acc3 = MFMA16(A1h, B1h, acc3);
    }
    *(f32x4*)&red[w][m][4 * q]           = acc0;   // v = 4q+r, token m
    *(f32x4*)&red[w][m][16 + 4 * q]      = acc1;
    *(f32x4*)&red[w][16 + m][4 * q]      = acc2;   // token 16+m
    *(f32x4*)&red[w][16 + m][16 + 4 * q] = acc3;
    __syncthreads();
    #pragma unroll
    for (int half = 0; half < 4; ++half) {
        int t = (tid >> 5) + half * 8, v = tid & 31;
        float s = bp[v];
        #pragma unroll
        for (int j = 0; j < 4; ++j) s += red[j][t][v];
        float sq = s * s;
        #pragma unroll
        for (int off = 1; off < 32; off <<= 1) sq += __shfl_xor(sq, off);
        float nv = s * (SC / sqrtf(sq));
        unsigned short hb2 = f2bf(nv);
        size_t idx = (size_t)(tok0 + t) * VDIM + v;
        hp_hi[idx] = hb2;
        hp_lo[idx] = f2bf(nv - bf2f(hb2));
    }
}

// ---------------------------------------------------------------------------
// k_vq: scores (3-product split fp32) -> exp2 -> argmax -> P@E^T (hi-only).
// 512 blocks x 256 threads (4 waves, launch_bounds(256,2): 2 blocks/CU).
// Verified R4/R6 body, unchanged (all schedule variants measured neutral;
// R7 fused-epilogue fence experiment was a 8x regression -> reverted).
// ---------------------------------------------------------------------------
__global__ __launch_bounds__(256, 2) void k_vq(const unsigned short* __restrict__ W,
                                               float* __restrict__ hvp,
                                               float* __restrict__ lp,
                                               float* __restrict__ amp,
                                               int* __restrict__ aip) {
    __shared__ __align__(16) unsigned short Eh[2][64 * 40];   // 20 KB total
    __shared__ __align__(16) unsigned short El[2][64 * 40];

    const unsigned short* E_hi  = W + OFS_E_HI;
    const unsigned short* E_lo  = W + OFS_E_LO;
    const unsigned short* Et_hi = W + OFS_ET_HI;
    const unsigned short* hp_hi = W + OFS_HP_HI;
    const unsigned short* hp_lo = W + OFS_HP_LO;

    int tid = threadIdx.x;
    int w = tid >> 6, l = tid & 63, q = l >> 4, m = l & 15;
    int tg = blockIdx.x >> 3, sp = blockIdx.x & 7;
    int tok0 = tg * 128 + w * 32;            // wave's 32 tokens (2 tiles)
    int cb0 = sp * 512;
    int sig = ((m & 12) << 1) | (m & 3);     // sigma(m) = 8*(m>>2)+(m&3)
    const f32x4 zero4 = {0.f, 0.f, 0.f, 0.f};

    // staging: 64 codes * 4 chunk16 = 256 16B-chunks; thread -> 1 hi + 1 lo
    int cs = tid >> 2, js = tid & 3;
    int lds_off = lsw(cs, js);
    size_t gs = (size_t)cs * VDIM + js * 8;

    size_t h0 = (size_t)(tok0 + m) * VDIM + q * 8;
    short8 hph0 = *(const short8*)(hp_hi + h0);
    short8 hpl0 = *(const short8*)(hp_lo + h0);
    short8 hph1 = *(const short8*)(hp_hi + h0 + 16 * VDIM);
    short8 hpl1 = *(const short8*)(hp_lo + h0 + 16 * VDIM);

    // prologue: stage tile 0 into buf 0
    {
        size_t tb = (size_t)cb0 * VDIM;
        short8 a = *(const short8*)(E_hi + tb + gs);
        short8 b = *(const short8*)(E_lo + tb + gs);
        *(short8*)&Eh[0][lds_off] = a;
        *(short8*)&El[0][lds_off] = b;
    }
    __syncthreads();

    f32x4 hv00 = zero4, hv01 = zero4, hv10 = zero4, hv11 = zero4;
    f32x2 ls0v = {0.f, 0.f}, ls1v = {0.f, 0.f};
    float am0 = -1e30f, am1 = -1e30f;
    int ai0 = 0, ai1 = 0;

    #pragma unroll 1
    for (int t = 0; t < 8; ++t) {            // 8 LDS tiles of 64 codes
        int buf = t & 1;
        short8 sa, sb;
        if (t < 7) {                         // issue next tile's staging loads
            size_t tb = (size_t)(cb0 + (t + 1) * 64) * VDIM;
            sa = *(const short8*)(E_hi + tb + gs);
            sb = *(const short8*)(E_lo + tb + gs);
        }
        int cbase = cb0 + t * 64;
        size_t tb0 = (size_t)sig * KCODES + cbase + q * 8;
        short8 T00 = *(const short8*)(Et_hi + tb0);
        short8 T01 = *(const short8*)(Et_hi + tb0 + (size_t)4 * KCODES);
        short8 T10 = *(const short8*)(Et_hi + tb0 + 32);
        short8 T11 = *(const short8*)(Et_hi + tb0 + 32 + (size_t)4 * KCODES);
        short8 E00h = *(const short8*)&Eh[buf][lsw(sig,          q)];
        short8 E00l = *(const short8*)&El[buf][lsw(sig,          q)];
        short8 E01h = *(const short8*)&Eh[buf][lsw(sig + 4,      q)];
        short8 E01l = *(const short8*)&El[buf][lsw(sig + 4,      q)];
        short8 E10h = *(const short8*)&Eh[buf][lsw(32 + sig,     q)];
        short8 E10l = *(const short8*)&El[buf][lsw(32 + sig,     q)];
        short8 E11h = *(const short8*)&Eh[buf][lsw(32 + sig + 4, q)];
        short8 E11l = *(const short8*)&El[buf][lsw(32 + sig + 4, q)];

        // ---- phase 1: all 24 score MFMAs (8 independent 3-deep chains) ----
        f32x4 sA0, sA1, sB0, sB1, sC0, sC1, sD0, sD1;
        sA0 = MFMA16(E00h, hpl0, zero4);     // chunk0 / tile0
        sA1 = MFMA16(E01h, hpl0, zero4);
        sB0 = MFMA16(E00h, hpl1, zero4);     // chunk0 / tile1
        sB1 = MFMA16(E01h, hpl1, zero4);
        sC0 = MFMA16(E10h, hpl0, zero4);     // chunk1 / tile0
        sC1 = MFMA16(E11h, hpl0, zero4);
        sD0 = MFMA16(E10h, hpl1, zero4);     // chunk1 / tile1
        sD1 = MFMA16(E11h, hpl1, zero4);
        sA0 = MFMA16(E00l, hph0, sA0);
        sA1 = MFMA16(E01l, hph0, sA1);
        sB0 = MFMA16(E00l, hph1, sB0);
        sB1 = MFMA16(E01l, hph1, sB1);
        sC0 = MFMA16(E10l, hph0, sC0);
        sC1 = MFMA16(E11l, hph0, sC1);
        sD0 = MFMA16(E10l, hph1, sD0);
        sD1 = MFMA16(E11l, hph1, sD1);
        sA0 = MFMA16(E00h, hph0, sA0);
        sA1 = MFMA16(E01h, hph0, sA1);
        sB0 = MFMA16(E00h, hph1, sB0);
        sB1 = MFMA16(E01h, hph1, sB1);
        sC0 = MFMA16(E10h, hph0, sC0);
        sC1 = MFMA16(E11h, hph0, sC1);
        sD0 = MFMA16(E10h, hph1, sD0);
        sD1 = MFMA16(E11h, hph1, sD1);

        // ---- phase 2: exp2 -> pack -> PV -> bookkeeping (order == R0) ----
        {
            int lbase = cbase + 8 * q;
            float p[8];
            #pragma unroll
            for (int r = 0; r < 4; ++r) { p[r] = fexp2(sA0[r]); p[4 + r] = fexp2(sA1[r]); }
            short8 Ph = pack8(p);
            hv00 = MFMA16(T00, Ph, hv00);
            hv01 = MFMA16(T01, Ph, hv01);
            #pragma unroll
            for (int r = 0; r < 4; ++r) {
                float sv = sA0[r];
                if (sv > am0) { am0 = sv; ai0 = lbase + r; }
                sv = sA1[r];
                if (sv > am0) { am0 = sv; ai0 = lbase + 4 + r; }
            }
            f32x2 pa = {p[0], p[1]}, pb = {p[2], p[3]};
            f32x2 pc = {p[4], p[5]}, pd = {p[6], p[7]};
            ls0v += (pa + pb) + (pc + pd);
        }
        {
            int lbase = cbase + 8 * q;
            float p[8];
            #pragma unroll
            for (int r = 0; r < 4; ++r) { p[r] = fexp2(sB0[r]); p[4 + r] = fexp2(sB1[r]); }
            short8 Ph = pack8(p);
            hv10 = MFMA16(T00, Ph, hv10);
            hv11 = MFMA16(T01, Ph, hv11);
            #pragma unroll
            for (int r = 0; r < 4; ++r) {
                float sv = sB0[r];
                if (sv > am1) { am1 = sv; ai1 = lbase + r; }
                sv = sB1[r];
                if (sv > am1) { am1 = sv; ai1 = lbase + 4 + r; }
            }
            f32x2 pa = {p[0], p[1]}, pb = {p[2], p[3]};
            f32x2 pc = {p[4], p[5]}, pd = {p[6], p[7]};
            ls1v += (pa + pb) + (pc + pd);
        }
        {
            int lbase = cbase + 32 + 8 * q;
            float p[8];
            #pragma unroll
            for (int r = 0; r < 4; ++r) { p[r] = fexp2(sC0[r]); p[4 + r] = fexp2(sC1[r]); }
            short8 Ph = pack8(p);
            hv00 = MFMA16(T10, Ph, hv00);
            hv01 = MFMA16(T11, Ph, hv01);
            #pragma unroll
            for (int r = 0; r < 4; ++r) {
                float sv = sC0[r];
                if (sv > am0) { am0 = sv; ai0 = lbase + r; }
                sv = sC1[r];
                if (sv > am0) { am0 = sv; ai0 = lbase + 4 + r; }
            }
            f32x2 pa = {p[0], p[1]}, pb = {p[2], p[3]};
            f32x2 pc = {p[4], p[5]}, pd = {p[6], p[7]};
            ls0v += (pa + pb) + (pc + pd);
        }
        {
            int lbase = cbase + 32 + 8 * q;
            float p[8];
            #pragma unroll
            for (int r = 0; r < 4; ++r) { p[r] = fexp2(sD0[r]); p[4 + r] = fexp2(sD1[r]); }
            short8 Ph = pack8(p);
            hv10 = MFMA16(T10, Ph, hv10);
            hv11 = MFMA16(T11, Ph, hv11);
            #pragma unroll
            for (int r = 0; r < 4; ++r) {
                float sv = sD0[r];
                if (sv > am1) { am1 = sv; ai1 = lbase + r; }
                sv = sD1[r];
                if (sv > am1) { am1 = sv; ai1 = lbase + 4 + r; }
            }
            f32x2 pa = {p[0], p[1]}, pb = {p[2], p[3]};
            f32x2 pc = {p[4], p[5]}, pd = {p[6], p[7]};
            ls1v += (pa + pb) + (pc + pd);
        }

        if (t < 7) {
            int nb = buf ^ 1;
            *(short8*)&Eh[nb][lds_off] = sa;
            *(short8*)&El[nb][lds_off] = sb;
            __syncthreads();
        }
    }

    float ls0 = ls0v.x + ls0v.y;
    float ls1 = ls1v.x + ls1v.y;
    // cross-q reduce (lane bits 4,5 share token column m)
    #pragma unroll
    for (int off = 16; off <= 32; off <<= 1) {
        ls0 += __shfl_xor(ls0, off);
        float a2 = __shfl_xor(am0, off);
        int   i2 = __shfl_xor(ai0, off);
        if (a2 > am0 || (a2 == am0 && i2 < ai0)) { am0 = a2; ai0 = i2; }
        ls1 += __shfl_xor(ls1, off);
        a2 = __shfl_xor(am1, off);
        i2 = __shfl_xor(ai1, off);
        if (a2 > am1 || (a2 == am1 && i2 < ai1)) { am1 = a2; ai1 = i2; }
    }
    size_t gtok = (size_t)sp * NTOK + tok0;
    if (q == 0) {
        lp[gtok + m] = ls0;      amp[gtok + m] = am0;      aip[gtok + m] = ai0;
        lp[gtok + 16 + m] = ls1; amp[gtok + 16 + m] = am1; aip[gtok + 16 + m] = ai1;
    }
    float* dst0 = hvp + (gtok + m) * VDIM;
    *(f32x4*)(dst0 + 8 * q)     = hv00;
    *(f32x4*)(dst0 + 8 * q + 4) = hv01;
    float* dst1 = hvp + (gtok + 16 + m) * VDIM;
    *(f32x4*)(dst1 + 8 * q)     = hv10;
    *(f32x4*)(dst1 + 8 * q + 4) = hv11;
}

// ---------------------------------------------------------------------------
// k_out: merge 8 partial splits -> softmax-normalize hv -> out = hv@Wpi^T+bpi.
// 256 blocks x 256 threads; 32 tokens/block (verified R6: two 16-token groups
// share each Wpi fragment load). Per-token FP op order identical to R3.
// ---------------------------------------------------------------------------
__global__ __launch_bounds__(256) void k_out(const unsigned short* __restrict__ W,
                                             const float* __restrict__ mask,
                                             const float* __restrict__ bpi,
                                             const float* __restrict__ hvp,
                                             const float* __restrict__ lp,
                                             const float* __restrict__ amp,
                                             const int* __restrict__ aip,
                                             float* __restrict__ out,
                                             float* __restrict__ code_out) {
    __shared__ float invl[32];
    __shared__ float lred[32][9];
    __shared__ float amred[32][9];
    __shared__ int   aired[32][9];
    __shared__ __align__(16) unsigned short hvh[32][40];
    __shared__ __align__(16) unsigned short hvl[32][40];
    const unsigned short* Wpi_hi = W + OFS_WPI_HI;
    const unsigned short* Wpi_lo = W + OFS_WPI_LO;
    int tid = threadIdx.x;
    int tok0 = blockIdx.x * 32;
    const f32x4 zero4 = {0.f, 0.f, 0.f, 0.f};

    {                                     // parallel merge loads (all 256)
        int t = tid >> 3, s = tid & 7;
        size_t gi = (size_t)s * NTOK + tok0 + t;
        lred[t][s]  = lp[gi];
        amred[t][s] = amp[gi];
        aired[t][s] = aip[gi];
    }
    __syncthreads();
    if (tid < 32) {
        float L = 0.f, A = -1e30f;
        int I = 0x7fffffff;
        #pragma unroll
        for (int s = 0; s < NSPLIT; ++s) {
            L += lred[tid][s];
            float a2 = amred[tid][s];
            int   i2 = aired[tid][s];
            if (a2 > A || (a2 == A && i2 < I)) { A = a2; I = i2; }
        }
        bool on = (mask[tok0 + tid] == 1.0f);
        code_out[tok0 + tid] = on ? (float)I : 0.0f;
        invl[tid] = on ? (1.0f / L) : 0.0f;
    }
    __syncthreads();
    {                                     // vectorized hv merge: 32t x 8 quads
        int t = tid >> 3, g = tid & 7;
        f32x4 x = zero4;
        #pragma unroll
        for (int sp = 0; sp < NSPLIT; ++sp)
            x += *(const f32x4*)&hvp[((size_t)sp * NTOK + tok0 + t) * VDIM + g * 4];
        float iv = invl[t];
        #pragma unroll
        for (int j = 0; j < 4; ++j) {
            float xv = x[j] * iv;
            unsigned short hb = f2bf(xv);
            hvh[t][g * 4 + j] = hb;
            hvl[t][g * 4 + j] = f2bf(xv - bf2f(hb));
        }
    }
    __syncthreads();
    int w = tid >> 6, l = tid & 63, q = l >> 4, m = l & 15;
    short8 gh0 = *(const short8*)&hvh[m][q * 8];
    short8 gl0 = *(const short8*)&hvl[m][q * 8];
    short8 gh1 = *(const short8*)&hvh[16 + m][q * 8];
    short8 gl1 = *(const short8*)&hvl[16 + m][q * 8];
    #pragma unroll
    for (int dt = 0; dt < 16; ++dt) {
        int dbase = w * 256 + dt * 16;
        short8 Ah = *(const short8*)(Wpi_hi + (size_t)(dbase + m) * VDIM + q * 8);
        short8 Al = *(const short8*)(Wpi_lo + (size_t)(dbase + m) * VDIM + q * 8);
        float4 bias = *(const float4*)(bpi + dbase + 4 * q);
        f32x4 o0 = MFMA16(Al, gh0, zero4);
        o0 = MFMA16(Ah, gl0, o0);
        o0 = MFMA16(Ah, gh0, o0);
        f32x4 o1 = MFMA16(Al, gh1, zero4);
        o1 = MFMA16(Ah, gl1, o1);
        o1 = MFMA16(Ah, gh1, o1);
        float4 r0 = make_float4(o0[0] + bias.x, o0[1] + bias.y,
                                o0[2] + bias.z, o0[3] + bias.w);
        *(float4*)(out + (size_t)(tok0 + m) * DIM + dbase + 4 * q) = r0;
        float4 r1 = make_float4(o1[0] + bias.x, o1[1] + bias.y,
                                o1[2] + bias.z, o1[3] + bias.w);
        *(float4*)(out + (size_t)(tok0 + 16 + m) * DIM + dbase + 4 * q) = r1;
    }
}

// ---------------------------------------------------------------------------
extern "C" void kernel_launch(void* const* d_in, const int* in_sizes, int n_in,
                              void* d_out, int out_size, void* d_ws, size_t ws_size,
                              hipStream_t stream) {
    const float* h    = (const float*)d_in[0];
    const float* mask = (const float*)d_in[1];
    const float* Wp   = (const float*)d_in[2];
    const float* bp   = (const float*)d_in[3];
    const float* Wpi  = (const float*)d_in[4];
    const float* bpi  = (const float*)d_in[5];
    const float* emb  = (const float*)d_in[6];
    float* out = (float*)d_out;

    unsigned short* W = (unsigned short*)d_ws;
    unsigned short* hp_hi = W + OFS_HP_HI;
    unsigned short* hp_lo = W + OFS_HP_LO;
    float* fbase = (float*)(W + F32_BASE);
    float* hvp = fbase + FOFS_HVP;
    float* lpp = fbase + FOFS_LP;
    float* ampp = fbase + FOFS_AMP;
    int*   aipp = (int*)(fbase + FOFS_AIP);

    float* code_out = out + (size_t)NTOK * DIM;
    float* loss_out = code_out + NTOK;

    hipLaunchKernelGGL(k_proj, dim3(336), dim3(256), 0, stream, h, Wp, bp, emb, Wpi, W, hp_hi, hp_lo, loss_out);
    hipLaunchKernelGGL(k_vq,   dim3(512), dim3(256), 0, stream, W, hvp, lpp, ampp, aipp);
    hipLaunchKernelGGL(k_out,  dim3(256), dim3(256), 0, stream, W, mask, bpi, hvp, lpp, ampp, aipp, out, code_out);
}